// Round 14
// baseline (33.912 us; speedup 1.0000x reference)
//
#include <hip/hip_runtime.h>

// out[b,h,w] = deblock( 2 * softmax(seq[f[b],t]+gum[b,t]) @ blocks ) / 2
// R14: TWO-KERNEL SPLIT.
//  K1 (grid 2048, 16 tiles/WG): softmax+matvec, stores 2*rec -> ws straight
//    from MFMA accumulators (1 barrier, no filter -> no seam/halo needed).
//    Small WGs give WG-turnover so late loads hide early tails.
//  K2 (grid 512): row-local deblock filter from ws -> out (R13 logic).
// nt loads+stores throughout (A/B-proven). Fallback to monolithic R13 if
// ws_size < 8 MB. Matvec: bf16 MFMA 16x16x32; den via ones-column MFMA.
// A/B-frags share the lane->k formula (HW k-interleave cancels over K).

#define NB       256
#define TIL      2048
#define EPITCH   264   // ushort pitch (528 B/row, 16B-aligned)
#define ROWPITCH 520   // float pitch for rows_img alias

typedef short  s8v __attribute__((ext_vector_type(8)));
typedef float  f4v __attribute__((ext_vector_type(4)));

__device__ __forceinline__ unsigned short f2bf(float f) {
    unsigned int u = __float_as_uint(f);
    u += 0x7fffu + ((u >> 16) & 1u);
    return (unsigned short)(u >> 16);
}

__device__ __forceinline__ unsigned int pk2(float a, float b) {
    return (unsigned int)f2bf(a) | ((unsigned int)f2bf(b) << 16);
}

__device__ __forceinline__ float4 ldnt4(const float* p) {
    float4 v;
    v.x = __builtin_nontemporal_load(p + 0);
    v.y = __builtin_nontemporal_load(p + 1);
    v.z = __builtin_nontemporal_load(p + 2);
    v.w = __builtin_nontemporal_load(p + 3);
    return v;
}

__device__ __forceinline__ float trilerp(const float* __restrict__ lutS,
                                         float x, float y, float z) {
    int x0 = (int)fminf(fmaxf(floorf(x), 0.0f), 1.0f);
    int y0 = (int)fminf(fmaxf(floorf(y), 0.0f), 1.0f);
    int z0 = (int)fminf(fmaxf(floorf(z), 0.0f), 1.0f);
    float xd = x - (float)x0;
    float yd = y - (float)y0;
    float zd = z - (float)z0;
    int base = x0 * 9 + y0 * 3 + z0;
    float c000 = lutS[base],     c100 = lutS[base + 9];
    float c010 = lutS[base + 3], c110 = lutS[base + 12];
    float c001 = lutS[base + 1], c101 = lutS[base + 10];
    float c011 = lutS[base + 4], c111 = lutS[base + 13];
    float xm = 1.0f - xd, ym = 1.0f - yd;
    float c00 = c000 * xm * ym + c100 * xd * ym + c010 * xm * yd + c110 * xd * yd;
    float c01 = c001 * xm * ym + c101 * xd * ym + c011 * xm * yd + c111 * xd * yd;
    return c00 * (1.0f - zd) + c01 * zd;
}

__device__ __forceinline__ float fval(const float* __restrict__ row,
                                      const float* __restrict__ fcolr, int x) {
    int x8 = x & 7;
    if (x8 == 0 || x8 == 7) return fcolr[(x >> 3) * 2 + (x8 == 7)];
    return row[x];
}

// ---------------- K1: softmax + matvec -> ws (2*rec), 16 tiles per WG ------
__global__ __launch_bounds__(256, 4)
void IR_matvec_kernel(
        const float* __restrict__ seq, const float* __restrict__ blocks,
        const float* __restrict__ gumbel, const int* __restrict__ fidx,
        float* __restrict__ ws)            // [16][32][8][512] = 2*rec image
{
    __shared__ __align__(16) unsigned short E[16 * EPITCH];  // 8448 B

    const int t    = threadIdx.x;
    const int lane = t & 63;
    const int wave = t >> 6;            // 0..3 -> N-strip
    const int bid  = blockIdx.x;
    const int b    = bid >> 7;          // 0..15
    const int hb   = (bid >> 2) & 31;   // 0..31
    const int qt   = bid & 3;           // 0..3 quarter-row

    const int f = fidx[b];
    const size_t tbase = (size_t)(hb * 64 + qt * 16) * NB;
    const float* sp = seq    + (size_t)f * (TIL * NB) + tbase;
    const float* gp = gumbel + (size_t)b * (TIL * NB) + tbase;

    // interleaved nt burst: 4+4 float4 per thread (16 tiles x 256 n)
    float4 lq[4], gq[4];
    #pragma unroll
    for (int r = 0; r < 4; ++r) {
        lq[r] = ldnt4(sp + (r * 256 + t) * 4);
        gq[r] = ldnt4(gp + (r * 256 + t) * 4);
    }

    // B-fragments (L2-hot 64 KB), same k-formula as A-frags
    const int g = lane >> 4;
    const int c = lane & 15;
    const float* bp = blocks + wave * 16 + c;
    s8v bfrag[8];
    #pragma unroll
    for (int ks = 0; ks < 8; ++ks) {
        int k0 = ks * 32 + g * 8;
        unsigned int u[4];
        #pragma unroll
        for (int jj = 0; jj < 4; ++jj)
            u[jj] = pk2(bp[(k0 + 2 * jj) * 64], bp[(k0 + 2 * jj + 1) * 64]);
        int4 iv = make_int4(u[0], u[1], u[2], u[3]);
        bfrag[ks] = __builtin_bit_cast(s8v, iv);
    }
    s8v ones;
    {
        unsigned int uo = (c == 0) ? 0x3F803F80u : 0u;
        int4 iv = make_int4(uo, uo, uo, uo);
        ones = __builtin_bit_cast(s8v, iv);
    }

    // pack: exp + bf16 -> E[tile][n]
    #pragma unroll
    for (int r = 0; r < 4; ++r) {
        int fi = r * 256 + t;               // f4 idx over 16*256 floats
        int tile = fi >> 6;
        int n    = (fi & 63) * 4;
        unsigned int u0 = pk2(__expf(lq[r].x + gq[r].x), __expf(lq[r].y + gq[r].y));
        unsigned int u1 = pk2(__expf(lq[r].z + gq[r].z), __expf(lq[r].w + gq[r].w));
        *(uint2*)&E[tile * EPITCH + n] = make_uint2(u0, u1);
    }
    __syncthreads();

    // MFMA: M=16 tiles, N-strip = wave*16.., K=256
    f4v acc = (f4v)0.0f, accd = (f4v)0.0f;
    #pragma unroll
    for (int ks = 0; ks < 8; ++ks) {
        s8v a = *(const s8v*)&E[c * EPITCH + ks * 32 + g * 8];
        acc  = __builtin_amdgcn_mfma_f32_16x16x32_bf16(a, bfrag[ks], acc,  0, 0, 0);
        accd = __builtin_amdgcn_mfma_f32_16x16x32_bf16(a, ones,      accd, 0, 0, 0);
    }

    // epilogue: normalize, store 2*rec straight to ws (no second barrier)
    float* wp = ws + ((size_t)(b * 32 + hb) * 8) * 512;
    const int p  = wave * 16 + c;          // pixel 0..63
    const int bh = p >> 3, bw = p & 7;
    #pragma unroll
    for (int rg = 0; rg < 4; ++rg) {
        float den = __shfl(accd[rg], (lane >> 4) * 16);
        float val = acc[rg] * (2.0f / den);
        int tl = g * 4 + rg;               // local tile 0..15
        int w  = (qt * 16 + tl) * 8 + bw;
        __builtin_nontemporal_store(val, wp + bh * 512 + w);
    }
}

// ---------------- K2: row-local deblocking filter ws -> out ----------------
__global__ __launch_bounds__(256, 4)
void IR_filter_kernel(const float* __restrict__ ws,
                      const float* __restrict__ lut,
                      float* __restrict__ out)
{
    __shared__ float rows_img[8 * ROWPITCH];
    __shared__ float fcol[8 * 128];
    __shared__ float lutS[28];

    const int t = threadIdx.x;
    if (t < 27) lutS[t] = lut[t];

    const float* ip = ws  + (size_t)blockIdx.x * (8 * 512);
    float*       op = out + (size_t)blockIdx.x * (8 * 512);

    // load 8x512 f32 (nt; ws is single-use)
    #pragma unroll
    for (int r = 0; r < 4; ++r) {
        int fi = r * 256 + t;               // f4 idx over 4096 floats
        float4 v = ldnt4(ip + fi * 4);
        int bh = fi >> 7, n = (fi & 127) * 4;
        *(float4*)&rows_img[bh * ROWPITCH + n] = v;
    }
    __syncthreads();

    // pass 1: boundary columns only
    #pragma unroll
    for (int it = 0; it < 4; ++it) {
        int idx = it * 256 + t;
        int bh = idx >> 7, ci = idx & 127;
        int w  = (ci >> 1) * 8 + ((ci & 1) ? 7 : 0);
        const float* row = rows_img + bh * ROWPITCH;
        int wm = (w > 0)   ? w - 1 : 0;
        int wp = (w < 511) ? w + 1 : 511;
        fcol[bh * 128 + ci] = trilerp(lutS, row[w], row[wm], row[wp]);
    }
    __syncthreads();

    // pass 2 + store (x-arg = ORIGINAL img per reference)
    #pragma unroll 2
    for (int it = 0; it < 16; ++it) {
        int pix = it * 256 + t;
        int bh = pix >> 9, w = pix & 511;
        const float* row = rows_img + bh * ROWPITCH;
        const float* fr  = fcol + bh * 128;
        float gv;
        if (bh == 0 || bh == 7) {
            int wm = (w > 0)   ? w - 1 : 0;
            int wp = (w < 511) ? w + 1 : 511;
            gv = trilerp(lutS, row[w], fval(row, fr, wm), fval(row, fr, wp));
        } else {
            gv = fval(row, fr, w);
        }
        __builtin_nontemporal_store(0.5f * gv, op + bh * 512 + w);
    }
}

// ---------------- Fallback: monolithic R13 (if ws too small) ---------------
__global__ __launch_bounds__(256, 2)
void IR_mono_kernel(
        const float* __restrict__ seq, const float* __restrict__ blocks,
        const float* __restrict__ lut, const float* __restrict__ gumbel,
        const int* __restrict__ fidx, float* __restrict__ out)
{
    __shared__ __align__(16) unsigned short E[64 * EPITCH];
    __shared__ float lutS[28];

    const int t    = threadIdx.x;
    const int lane = t & 63;
    const int wave = t >> 6;
    const int b    = blockIdx.x >> 5;
    const int hb   = blockIdx.x & 31;

    if (t < 27) lutS[t] = lut[t];

    const int f = fidx[b];
    const float* sp = seq    + (size_t)f * (TIL * NB) + (size_t)hb * (64 * NB);
    const float* gp = gumbel + (size_t)b * (TIL * NB) + (size_t)hb * (64 * NB);

    float4 lq[16], gq[16];
    #pragma unroll
    for (int r = 0; r < 16; ++r) {
        lq[r] = ldnt4(sp + (r * 256 + t) * 4);
        gq[r] = ldnt4(gp + (r * 256 + t) * 4);
    }
    #pragma unroll
    for (int r = 0; r < 16; ++r) {
        int fi = r * 256 + t;
        int tile = fi >> 6;
        int n    = (fi & 63) * 4;
        unsigned int u0 = pk2(__expf(lq[r].x + gq[r].x), __expf(lq[r].y + gq[r].y));
        unsigned int u1 = pk2(__expf(lq[r].z + gq[r].z), __expf(lq[r].w + gq[r].w));
        *(uint2*)&E[tile * EPITCH + n] = make_uint2(u0, u1);
    }

    const int g = lane >> 4;
    const int c = lane & 15;
    const float* bp = blocks + wave * 16 + c;
    s8v bfrag[8];
    #pragma unroll
    for (int ks = 0; ks < 8; ++ks) {
        int k0 = ks * 32 + g * 8;
        unsigned int u[4];
        #pragma unroll
        for (int jj = 0; jj < 4; ++jj)
            u[jj] = pk2(bp[(k0 + 2 * jj) * 64], bp[(k0 + 2 * jj + 1) * 64]);
        int4 iv = make_int4(u[0], u[1], u[2], u[3]);
        bfrag[ks] = __builtin_bit_cast(s8v, iv);
    }
    s8v ones;
    {
        unsigned int uo = (c == 0) ? 0x3F803F80u : 0u;
        int4 iv = make_int4(uo, uo, uo, uo);
        ones = __builtin_bit_cast(s8v, iv);
    }
    __syncthreads();

    f4v acc[4], accd[4];
    #pragma unroll
    for (int mt = 0; mt < 4; ++mt) { acc[mt] = (f4v)0.0f; accd[mt] = (f4v)0.0f; }
    #pragma unroll
    for (int ks = 0; ks < 8; ++ks) {
        #pragma unroll
        for (int mt = 0; mt < 4; ++mt) {
            s8v a = *(const s8v*)&E[(mt * 16 + c) * EPITCH + ks * 32 + g * 8];
            acc[mt]  = __builtin_amdgcn_mfma_f32_16x16x32_bf16(a, bfrag[ks], acc[mt],  0, 0, 0);
            accd[mt] = __builtin_amdgcn_mfma_f32_16x16x32_bf16(a, ones,      accd[mt], 0, 0, 0);
        }
    }
    __syncthreads();

    float* rows_img = (float*)E;
    float* fcol     = (float*)E + 8 * ROWPITCH;
    #pragma unroll
    for (int mt = 0; mt < 4; ++mt) {
        #pragma unroll
        for (int rg = 0; rg < 4; ++rg) {
            float den = __shfl(accd[mt][rg], (lane >> 4) * 16);
            float val = acc[mt][rg] * (2.0f / den);
            int row = mt * 16 + g * 4 + rg;
            int p   = wave * 16 + c;
            int bh  = p >> 3, bw = p & 7;
            rows_img[bh * ROWPITCH + row * 8 + bw] = val;
        }
    }
    __syncthreads();

    #pragma unroll
    for (int it = 0; it < 4; ++it) {
        int idx = it * 256 + t;
        int bh = idx >> 7, ci = idx & 127;
        int w  = (ci >> 1) * 8 + ((ci & 1) ? 7 : 0);
        const float* row = rows_img + bh * ROWPITCH;
        int wm = (w > 0)   ? w - 1 : 0;
        int wp = (w < 511) ? w + 1 : 511;
        fcol[bh * 128 + ci] = trilerp(lutS, row[w], row[wm], row[wp]);
    }
    __syncthreads();

    float* op = out + (size_t)blockIdx.x * (8 * 512);
    #pragma unroll 2
    for (int it = 0; it < 16; ++it) {
        int pix = it * 256 + t;
        int bh = pix >> 9, w = pix & 511;
        const float* row = rows_img + bh * ROWPITCH;
        const float* fr  = fcol + bh * 128;
        float gv;
        if (bh == 0 || bh == 7) {
            int wm = (w > 0)   ? w - 1 : 0;
            int wp = (w < 511) ? w + 1 : 511;
            gv = trilerp(lutS, row[w], fval(row, fr, wm), fval(row, fr, wp));
        } else {
            gv = fval(row, fr, w);
        }
        __builtin_nontemporal_store(0.5f * gv, op + bh * 512 + w);
    }
}

extern "C" void kernel_launch(void* const* d_in, const int* in_sizes, int n_in,
                              void* d_out, int out_size, void* d_ws, size_t ws_size,
                              hipStream_t stream) {
    const float* seq    = (const float*)d_in[0];
    const float* blocks = (const float*)d_in[1];
    const float* lut    = (const float*)d_in[2];
    const float* gumbel = (const float*)d_in[3];
    const int*   fidx   = (const int*)d_in[4];
    float* out = (float*)d_out;

    const size_t need = (size_t)16 * 256 * 512 * sizeof(float);   // 8 MB
    if (ws_size >= need) {
        float* ws = (float*)d_ws;
        IR_matvec_kernel<<<dim3(2048), dim3(256), 0, stream>>>(
            seq, blocks, gumbel, fidx, ws);
        IR_filter_kernel<<<dim3(512), dim3(256), 0, stream>>>(ws, lut, out);
    } else {
        IR_mono_kernel<<<dim3(512), dim3(256), 0, stream>>>(
            seq, blocks, lut, gumbel, fidx, out);
    }
}

// Round 15
// 19.995 us; speedup vs baseline: 1.6961x; 1.6961x over previous
//
#include <hip/hip_runtime.h>

// out[b,h,w] = deblock( 2 * softmax(seq[f[b],t]+gum[b,t]) @ blocks ) / 2
// One WG per (b, hb): 64 tiles x 256 softmax + matvec + row-local deblock.
// R15 = exact revert to R13 (best: 19.97us). Ledger: nt loads (-2.2us) +
// nt stores (-1.7us) + interleaved lq/gq issue (-0.35us); all structural
// levers (waves, WG/CU, MLP depth, instr count, 2-row pipeline, split+halo,
// 2-kernel split) flat or negative. R14's split showed per-kernel fixed
// overhead ~5-10us => R13's active streaming is ~12-14us for 75.5 MB
// (~5.4-6.3 TB/s) = at the measured achievable HBM ceiling.
// Matvec via bf16 MFMA 16x16x32; softmax den via ones-column MFMA (col 0).
// A/B-frags share the lane->k formula (HW k-interleave cancels over K).
// Filter: pass1 only boundary cols -> fcol; pass2 x-arg = ORIGINAL img.

#define NB       256
#define TIL      2048
#define EPITCH   264   // ushort pitch (528 B/row, 16B-aligned)
#define ROWPITCH 520   // float pitch for rows_img alias

typedef short  s8v __attribute__((ext_vector_type(8)));  // 8 bf16 = 4 VGPR
typedef float  f4v __attribute__((ext_vector_type(4)));  // 4 f32 acc

__device__ __forceinline__ unsigned short f2bf(float f) {
    unsigned int u = __float_as_uint(f);
    u += 0x7fffu + ((u >> 16) & 1u);      // round-to-nearest-even
    return (unsigned short)(u >> 16);
}

__device__ __forceinline__ unsigned int pk2(float a, float b) {
    return (unsigned int)f2bf(a) | ((unsigned int)f2bf(b) << 16);
}

__device__ __forceinline__ float4 ldnt4(const float* p) {
    float4 v;
    v.x = __builtin_nontemporal_load(p + 0);
    v.y = __builtin_nontemporal_load(p + 1);
    v.z = __builtin_nontemporal_load(p + 2);
    v.w = __builtin_nontemporal_load(p + 3);
    return v;   // folds to global_load_dwordx4 nt
}

__device__ __forceinline__ float trilerp(const float* __restrict__ lutS,
                                         float x, float y, float z) {
    int x0 = (int)fminf(fmaxf(floorf(x), 0.0f), 1.0f);
    int y0 = (int)fminf(fmaxf(floorf(y), 0.0f), 1.0f);
    int z0 = (int)fminf(fmaxf(floorf(z), 0.0f), 1.0f);
    float xd = x - (float)x0;
    float yd = y - (float)y0;
    float zd = z - (float)z0;
    int base = x0 * 9 + y0 * 3 + z0;
    float c000 = lutS[base],     c100 = lutS[base + 9];
    float c010 = lutS[base + 3], c110 = lutS[base + 12];
    float c001 = lutS[base + 1], c101 = lutS[base + 10];
    float c011 = lutS[base + 4], c111 = lutS[base + 13];
    float xm = 1.0f - xd, ym = 1.0f - yd;
    float c00 = c000 * xm * ym + c100 * xd * ym + c010 * xm * yd + c110 * xd * yd;
    float c01 = c001 * xm * ym + c101 * xd * ym + c011 * xm * yd + c111 * xd * yd;
    return c00 * (1.0f - zd) + c01 * zd;
}

__device__ __forceinline__ float fval(const float* __restrict__ row,
                                      const float* __restrict__ fcolr, int x) {
    int x8 = x & 7;
    if (x8 == 0 || x8 == 7) return fcolr[(x >> 3) * 2 + (x8 == 7)];
    return row[x];
}

__global__ __launch_bounds__(256, 2)
void ImageReconstruction_46523085751029_kernel(
        const float* __restrict__ seq,      // [256][2048][256]
        const float* __restrict__ blocks,   // [256][64]
        const float* __restrict__ lut,      // [27]
        const float* __restrict__ gumbel,   // [16][2048][256]
        const int*   __restrict__ fidx,     // [16]
        float*       __restrict__ out)      // [16][256][512]
{
    __shared__ __align__(16) unsigned short E[64 * EPITCH];  // 33792 B; aliased later
    __shared__ float lutS[28];

    const int t    = threadIdx.x;
    const int lane = t & 63;
    const int wave = t >> 6;          // 0..3 -> N-strip
    const int b    = blockIdx.x >> 5;
    const int hb   = blockIdx.x & 31;

    if (t < 27) lutS[t] = lut[t];

    const int f = fidx[b];
    const float* sp = seq    + (size_t)f * (TIL * NB) + (size_t)hb * (64 * NB);
    const float* gp = gumbel + (size_t)b * (TIL * NB) + (size_t)hb * (64 * NB);

    // ---- P1a: burst-issue ALL loads, INTERLEAVED lq/gq pairs so consume of
    //           pair r is only ~2 loads deep in the vmcnt queue
    float4 lq[16], gq[16];
    #pragma unroll
    for (int r = 0; r < 16; ++r) {
        lq[r] = ldnt4(sp + (r * 256 + t) * 4);
        gq[r] = ldnt4(gp + (r * 256 + t) * 4);
    }

    // ---- P1b: exp + bf16 pack -> E[tile][n]  (no max-sub: |x|<=~22, f32-safe)
    #pragma unroll
    for (int r = 0; r < 16; ++r) {
        int fi = r * 256 + t;                       // float4 idx over 64*256 floats
        int tile = fi >> 6;
        int n    = (fi & 63) * 4;
        unsigned int u0 = pk2(__expf(lq[r].x + gq[r].x), __expf(lq[r].y + gq[r].y));
        unsigned int u1 = pk2(__expf(lq[r].z + gq[r].z), __expf(lq[r].w + gq[r].w));
        *(uint2*)&E[tile * EPITCH + n] = make_uint2(u0, u1);   // 8B aligned
    }

    // ---- B-fragments from global (L2-hot 64 KB), same k-formula as A-frags
    const int g = lane >> 4;       // k-group
    const int c = lane & 15;       // N-index within strip
    const float* bp = blocks + wave * 16 + c;      // column base
    s8v bfrag[8];
    #pragma unroll
    for (int ks = 0; ks < 8; ++ks) {
        int k0 = ks * 32 + g * 8;
        unsigned int u[4];
        #pragma unroll
        for (int jj = 0; jj < 4; ++jj)
            u[jj] = pk2(bp[(k0 + 2 * jj) * 64], bp[(k0 + 2 * jj + 1) * 64]);
        int4 iv = make_int4(u[0], u[1], u[2], u[3]);
        bfrag[ks] = __builtin_bit_cast(s8v, iv);
    }
    s8v ones;
    {
        unsigned int uo = (c == 0) ? 0x3F803F80u : 0u;
        int4 iv = make_int4(uo, uo, uo, uo);
        ones = __builtin_bit_cast(s8v, iv);
    }

    __syncthreads();

    // ---- P2: MFMA. Wave: N-strip = wave, all 4 M-tiles, K=256.
    f4v acc[4], accd[4];
    #pragma unroll
    for (int mt = 0; mt < 4; ++mt) { acc[mt] = (f4v)0.0f; accd[mt] = (f4v)0.0f; }

    #pragma unroll
    for (int ks = 0; ks < 8; ++ks) {
        #pragma unroll
        for (int mt = 0; mt < 4; ++mt) {
            s8v a = *(const s8v*)&E[(mt * 16 + c) * EPITCH + ks * 32 + g * 8];
            acc[mt]  = __builtin_amdgcn_mfma_f32_16x16x32_bf16(a, bfrag[ks], acc[mt],  0, 0, 0);
            accd[mt] = __builtin_amdgcn_mfma_f32_16x16x32_bf16(a, ones,      accd[mt], 0, 0, 0);
        }
    }

    __syncthreads();   // all E reads done; safe to alias

    // ---- normalize (den from accd col 0 of each row) -> rows_img
    float* rows_img = (float*)E;                    // [8][520] = 16640 B
    float* fcol     = (float*)E + 8 * ROWPITCH;     // [8][128] =  4096 B (tot 20736)

    #pragma unroll
    for (int mt = 0; mt < 4; ++mt) {
        #pragma unroll
        for (int rg = 0; rg < 4; ++rg) {
            float den = __shfl(accd[mt][rg], (lane >> 4) * 16);
            float val = acc[mt][rg] * (2.0f / den);
            int row = mt * 16 + g * 4 + rg;      // tile index wb (0..63)
            int p   = wave * 16 + c;             // pixel 0..63 in tile
            int bh  = p >> 3, bw = p & 7;
            rows_img[bh * ROWPITCH + row * 8 + bw] = val;
        }
    }
    __syncthreads();

    // ---- Pass 1: horizontal filter ONLY at boundary columns (w%8 in {0,7})
    #pragma unroll
    for (int it = 0; it < 4; ++it) {
        int idx = it * 256 + t;                  // 0..1023
        int bh = idx >> 7, ci = idx & 127;
        int w  = (ci >> 1) * 8 + ((ci & 1) ? 7 : 0);
        const float* row = rows_img + bh * ROWPITCH;
        int wm = (w > 0)   ? w - 1 : 0;
        int wp = (w < 511) ? w + 1 : 511;
        fcol[bh * 128 + ci] = trilerp(lutS, row[w], row[wm], row[wp]);
    }
    __syncthreads();

    // ---- Pass 2 + store (rows h%8 in {0,7} filter; x-arg = ORIGINAL img)
    float* op = out + (size_t)b * (256 * 512) + (size_t)hb * (8 * 512);
    #pragma unroll 2
    for (int it = 0; it < 16; ++it) {
        int pix = it * 256 + t;
        int bh = pix >> 9, w = pix & 511;        // bh wave-uniform per it
        const float* row = rows_img + bh * ROWPITCH;
        const float* fr  = fcol + bh * 128;
        float gv;
        if (bh == 0 || bh == 7) {
            int wm = (w > 0)   ? w - 1 : 0;
            int wp = (w < 511) ? w + 1 : 511;
            gv = trilerp(lutS, row[w], fval(row, fr, wm), fval(row, fr, wp));
        } else {
            gv = fval(row, fr, w);
        }
        __builtin_nontemporal_store(0.5f * gv, op + bh * 512 + w);
    }
}

extern "C" void kernel_launch(void* const* d_in, const int* in_sizes, int n_in,
                              void* d_out, int out_size, void* d_ws, size_t ws_size,
                              hipStream_t stream) {
    const float* seq    = (const float*)d_in[0];
    const float* blocks = (const float*)d_in[1];
    const float* lut    = (const float*)d_in[2];
    const float* gumbel = (const float*)d_in[3];
    const int*   fidx   = (const int*)d_in[4];
    float* out = (float*)d_out;

    dim3 grid(512);   // 16 batches x 32 tile-rows
    dim3 block(256);
    ImageReconstruction_46523085751029_kernel<<<grid, block, 0, stream>>>(
        seq, blocks, lut, gumbel, fidx, out);
}